// Round 2
// baseline (11116.502 us; speedup 1.0000x reference)
//
#include <hip/hip_runtime.h>
#include <stdint.h>

// Autoregressive bidirectional 2-layer LSTM encoder, MI355X persistent kernel.
// B=32, T=512, IN=OUT=512, LH=512 per direction, LSTM_IN=1024.
//
// Feedback folding: pred(t-1) enters layer-0 gates linearly => precompute
// Wcomb = Wp @ Wfc  ([2048,512]@[512,1024]) per direction; recurrence then
// only needs h0,h1 (2 grid barriers/step instead of 3). FC head computed as
// K-split partials off the critical path, finalized 2 steps later.
//
// 256 WGs x 256 thr (1/CU). Per WG: 16 gate rows (4 units x {i,f,g,o}) per
// phase, weights bf16 LDS-resident (112KB), mfma_f32_16x16x32_bf16,
// A/B fragments use the SAME per-lane k packing (k = 32*ks + 8*(lane>>4)+j)
// so the true HW k-order cancels. C/D: col=lane&15, row=(lane>>4)*4+reg.

#define TT 512
#define NWG 256

typedef __attribute__((ext_vector_type(8))) short short8;
typedef __attribute__((ext_vector_type(4))) float f32x4;
typedef __attribute__((ext_vector_type(4))) unsigned short ushort4v;
typedef __attribute__((ext_vector_type(4))) float float4v;

__device__ __forceinline__ unsigned short f2bf(float f) {
  unsigned int u = __float_as_uint(f);
  u = (u + 0x7fffu + ((u >> 16) & 1u)) >> 16;
  return (unsigned short)u;
}

// ---------------- prep kernels ----------------

// input_seq [32][512][512] f32 -> xbf [512][32][512] bf16
__global__ void xconv_kernel(const float* __restrict__ src,
                             unsigned short* __restrict__ dst) {
  int vid = blockIdx.x * 256 + threadIdx.x;
  if (vid >= 2097152) return;
  int d0 = vid * 4;
  int t = d0 >> 14;
  int r = d0 & 16383;
  int b = r >> 9;
  int k = r & 511;
  float4v v = *(const float4v*)(src + ((size_t)(b * 512 + t) * 512 + k));
  ushort4v o;
#pragma unroll
  for (int i = 0; i < 4; ++i) o[i] = f2bf(v[i]);
  *(ushort4v*)(dst + d0) = o;
}

// Wcomb[d][r][h] = sum_o Wih[0,d,r,512+o] * Wfc[o,h], written straight into
// packedA's kstep 16..47 region in MFMA B-fragment order (bf16).
__global__ void wcomb_kernel(const float* __restrict__ Wih,
                             const float* __restrict__ Wfc,
                             unsigned short* __restrict__ packA) {
  int bid = blockIdx.x;                 // 2048 blocks
  int h = (bid & 3) * 256 + threadIdx.x;
  int rg = bid >> 2;                    // 0..511
  int d = rg >> 8;
  int r0 = (rg & 255) * 8;
  float acc[8];
#pragma unroll
  for (int i = 0; i < 8; ++i) acc[i] = 0.f;
  const float* wrow = Wih + (size_t)(d * 2048) * 1024;
  for (int o = 0; o < 512; ++o) {
    float f = Wfc[(size_t)o * 1024 + h];
#pragma unroll
    for (int i = 0; i < 8; ++i)
      acc[i] += wrow[(size_t)(r0 + i) * 1024 + 512 + o] * f;
  }
#pragma unroll
  for (int i = 0; i < 8; ++i) {
    int rr = r0 + i;
    int q = rr >> 9, u = rr & 511;
    int wg = d * 128 + (u >> 2);
    int n = q * 4 + (u & 3);
    int k = 512 + h;
    int ks = k >> 5, kin = k & 31;
    int g = kin >> 3, j = kin & 7;
    int e = (n + 16 * g) * 8 + j;
    packA[((size_t)wg * 64 + ks) * 512 + e] = f2bf(acc[i]);
  }
}

// Pack raw weights (bf16, MFMA B-fragment order):
// packedA[wg][64ks][512]: ks 0..15 = Wx (Wih L0 cols 0..511), 48..63 = Whh L0.
// packedB[wg][48ks][512]: ks 0..31 = Wih L1, 32..47 = Whh L1.
// packedFC[q][32ks][512]: Wfc tiles.
__global__ void pack_kernel(const float* __restrict__ Wih,
                            const float* __restrict__ Whh,
                            const float* __restrict__ Wfc,
                            unsigned short* __restrict__ packA,
                            unsigned short* __restrict__ packB,
                            unsigned short* __restrict__ packFC) {
  const int NA = 256 * 32 * 512;
  const int NB = 256 * 48 * 512;
  const int NFC = 32 * 32 * 512;
  int i = blockIdx.x * 256 + threadIdx.x;
  if (i < NA) {
    int wg = i >> 14;
    int rem = i & 16383;
    int ksl = rem >> 9;
    int e = rem & 511;
    int ks = (ksl < 16) ? ksl : ksl + 32;
    int l = e >> 3, j = e & 7;
    int n = l & 15, g = l >> 4;
    int k = ks * 32 + 8 * g + j;
    int d = wg >> 7, u0 = (wg & 127) << 2;
    int r = (n >> 2) * 512 + u0 + (n & 3);
    float v;
    if (k < 512) v = Wih[(size_t)(d * 2048 + r) * 1024 + k];
    else v = Whh[(size_t)(d * 2048 + r) * 512 + (k - 1536)];
    packA[((size_t)wg * 64 + ks) * 512 + e] = f2bf(v);
  } else if (i < NA + NB) {
    int ii = i - NA;
    int wg = ii / 24576;
    int rem = ii - wg * 24576;
    int ks = rem >> 9;
    int e = rem & 511;
    int l = e >> 3, j = e & 7;
    int n = l & 15, g = l >> 4;
    int k = ks * 32 + 8 * g + j;
    int d = wg >> 7, u0 = (wg & 127) << 2;
    int r = (n >> 2) * 512 + u0 + (n & 3);
    float v;
    if (k < 1024) v = Wih[(size_t)((2 + d) * 2048 + r) * 1024 + k];
    else v = Whh[(size_t)((2 + d) * 2048 + r) * 512 + (k - 1024)];
    packB[((size_t)wg * 48 + ks) * 512 + e] = f2bf(v);
  } else if (i < NA + NB + NFC) {
    int ii = i - NA - NB;
    int q = ii >> 14;
    int rem = ii & 16383;
    int ks = rem >> 9;
    int e = rem & 511;
    int l = e >> 3, j = e & 7;
    int n = l & 15, g = l >> 4;
    int k = ks * 32 + 8 * g + j;
    int o = q * 16 + n;
    packFC[((size_t)q * 32 + ks) * 512 + e] = f2bf(Wfc[(size_t)o * 1024 + k]);
  }
}

// biasA0 = bih+bhh (L0); bpf = Wp @ bfc (added for t>0); biasB = bih+bhh (L1)
__global__ void bias_kernel(const float* __restrict__ Wih,
                            const float* __restrict__ bih,
                            const float* __restrict__ bhh,
                            const float* __restrict__ bfc,
                            float* __restrict__ biasA0,
                            float* __restrict__ bpf,
                            float* __restrict__ biasB) {
  int r = blockIdx.x * 256 + threadIdx.x;  // 4096
  int d = r >> 11, rr = r & 2047;
  biasA0[r] = bih[d * 2048 + rr] + bhh[d * 2048 + rr];
  biasB[r] = bih[(2 + d) * 2048 + rr] + bhh[(2 + d) * 2048 + rr];
  float s = 0.f;
  const float* w = Wih + (size_t)(d * 2048 + rr) * 1024 + 512;
  for (int o = 0; o < 512; ++o) s += w[o] * bfc[o];
  bpf[r] = s;
}

// ---------------- main persistent kernel ----------------

__device__ __forceinline__ void gridbar(int* flags, int gen) {
  __syncthreads();  // compiler drains vmcnt before s_barrier -> sc1 stores done
  if (threadIdx.x == 0)
    __hip_atomic_store(&flags[blockIdx.x], gen, __ATOMIC_RELAXED,
                       __HIP_MEMORY_SCOPE_AGENT);
  while (__hip_atomic_load(&flags[threadIdx.x], __ATOMIC_RELAXED,
                           __HIP_MEMORY_SCOPE_AGENT) < gen)
    __builtin_amdgcn_s_sleep(2);
  __syncthreads();
  if (threadIdx.x < 64)  // one acquire (buffer_inv) per WG covers CU L1 + XCD L2
    __builtin_amdgcn_fence(__ATOMIC_ACQUIRE, "agent");
  __syncthreads();
}

__global__ __launch_bounds__(256, 1) void rnn_main(
    const unsigned short* __restrict__ xbf,
    const unsigned short* __restrict__ packA,
    const unsigned short* __restrict__ packB,
    const unsigned short* __restrict__ packFC,
    const float* __restrict__ biasA0, const float* __restrict__ bpf,
    const float* __restrict__ biasB, const float* __restrict__ bfc,
    unsigned short* __restrict__ hws, float* __restrict__ fcpart,
    int* __restrict__ flags, float* __restrict__ dout) {
  extern __shared__ unsigned short lds[];
  unsigned short* wA = lds;            // 64*512 bf16 = 64KB
  unsigned short* wB = wA + 64 * 512;  // 48*512 bf16 = 48KB
  float* red = (float*)(wB + 48 * 512);  // 2048 f32
  float* red2 = red + 2048;              // 2048 f32  (total 128KB)

  const int wg = blockIdx.x;
  const int tid = threadIdx.x;
  const int wv = tid >> 6;
  const int lane = tid & 63;
  const int d = wg >> 7;
  const int u0 = (wg & 127) << 2;
  const int frow = lane & 15;
  const int fk = (lane >> 4) << 3;
  const int fcq = wg >> 3;
  const int fcs = wg & 7;

  {  // stage LDS-resident weights
    const uint4* s = (const uint4*)(packA + (size_t)wg * (64 * 512));
    uint4* dd = (uint4*)wA;
    for (int i = tid; i < 4096; i += 256) dd[i] = s[i];
    const uint4* s2 = (const uint4*)(packB + (size_t)wg * (48 * 512));
    uint4* dd2 = (uint4*)wB;
    for (int i = tid; i < 3072; i += 256) dd2[i] = s2[i];
  }
  __syncthreads();

  float c0 = 0.f, c1 = 0.f;  // cell state, persistent in registers
  const int ab = tid >> 2;   // batch (tid<128)
  const int au = tid & 3;    // unit-in-4

  float* out = dout;
  float* hn = dout + (size_t)32 * 512 * 512;
  float* cn = hn + 4 * 32 * 512;
  f32x4 zz = {0.f, 0.f, 0.f, 0.f};

  for (int t = 0; t < TT; ++t) {
    const int oldp = t & 1;
    const unsigned short* h0o = hws + oldp * 65536;
    const unsigned short* h1o = h0o + 32768;
    unsigned short* h0n = hws + (oldp ^ 1) * 65536;
    unsigned short* h1n = h0n + 32768;

    // finalize pred(t-2) from fcpart (off critical path)
    if (wg < 32 && t >= 2) {
      for (int ii = tid; ii < 512; ii += 256) {
        int b = ii >> 4, n = ii & 15;
        float s = bfc[wg * 16 + n];
#pragma unroll
        for (int ss = 0; ss < 8; ++ss)
          s += fcpart[(size_t)(wg * 8 + ss) * 512 + b * 16 + n];
        out[(size_t)b * 262144 + (size_t)(t - 2) * 512 + wg * 16 + n] = s;
      }
    }

    // ---- Phase A: layer-0 gates. K = [x 512 | h1@Wcomb 1024 | h0dir 512]
    f32x4 acc0 = zz, acc1 = zz;
    {
      const unsigned short* xb = xbf + (size_t)t * 16384;
      const unsigned short* abase;
      int astride;
      if (wv == 0) { abase = xb; astride = 512; }
      else if (wv == 3) { abase = h0o + d * 512; astride = 1024; }
      else { abase = h1o + (wv - 1) * 512; astride = 1024; }
      for (int li = 0; li < 16; ++li) {
        const unsigned short* ap = abase + li * 32 + fk;
        short8 a0 = *(const short8*)(ap + (size_t)frow * astride);
        short8 a1 = *(const short8*)(ap + (size_t)(frow + 16) * astride);
        short8 bb = *(const short8*)(wA + (wv * 16 + li) * 512 + lane * 8);
        acc0 = __builtin_amdgcn_mfma_f32_16x16x32_bf16(a0, bb, acc0, 0, 0, 0);
        acc1 = __builtin_amdgcn_mfma_f32_16x16x32_bf16(a1, bb, acc1, 0, 0, 0);
      }
    }
    {
      float* r0 = red + (wv * 2 + 0) * 256;
      float* r1 = red + (wv * 2 + 1) * 256;
      int cc = lane & 15, rb = (lane >> 4) * 4;
#pragma unroll
      for (int q = 0; q < 4; ++q) {
        r0[(rb + q) * 16 + cc] = acc0[q];
        r1[(rb + q) * 16 + cc] = acc1[q];
      }
    }
    __syncthreads();
    if (tid < 128) {
      int mt = ab >> 4, rr = ab & 15;
      float g[4];
#pragma unroll
      for (int q = 0; q < 4; ++q) {
        int cc = q * 4 + au;
        float s = 0.f;
#pragma unroll
        for (int w = 0; w < 4; ++w) s += red[(w * 2 + mt) * 256 + rr * 16 + cc];
        int gi = d * 2048 + q * 512 + u0 + au;
        s += biasA0[gi];
        if (t > 0) s += bpf[gi];
        g[q] = s;
      }
      float ig = 1.f / (1.f + __expf(-g[0]));
      float fg = 1.f / (1.f + __expf(-g[1]));
      float gv = tanhf(g[2]);
      float og = 1.f / (1.f + __expf(-g[3]));
      c0 = fg * c0 + ig * gv;
      float h = og * tanhf(c0);
      unsigned int hv = (unsigned int)f2bf(h);
      unsigned int pv = (unsigned int)__shfl_xor((int)hv, 1);
      if ((au & 1) == 0) {
        unsigned int word = hv | (pv << 16);
        __hip_atomic_store((unsigned int*)(h0n + ab * 1024 + d * 512 + u0 + au),
                           word, __ATOMIC_RELAXED, __HIP_MEMORY_SCOPE_AGENT);
      }
      if (t == TT - 1) {
        hn[(size_t)(d * 32 + ab) * 512 + u0 + au] = h;
        cn[(size_t)(d * 32 + ab) * 512 + u0 + au] = c0;
      }
    }
    gridbar(flags, 2 * t + 1);

    // ---- Phase B: layer-1 gates (K = [h0 1024 | h1dir 512]) + FC partials
    acc0 = zz; acc1 = zz;
    for (int kk = 0; kk < 12; ++kk) {
      int ks = wv * 12 + kk;
      const unsigned short* ap = (ks < 32)
          ? (h0n + ks * 32 + fk)
          : (h1o + d * 512 + (ks - 32) * 32 + fk);
      short8 a0 = *(const short8*)(ap + (size_t)frow * 1024);
      short8 a1 = *(const short8*)(ap + (size_t)(frow + 16) * 1024);
      short8 bb = *(const short8*)(wB + ks * 512 + lane * 8);
      acc0 = __builtin_amdgcn_mfma_f32_16x16x32_bf16(a0, bb, acc0, 0, 0, 0);
      acc1 = __builtin_amdgcn_mfma_f32_16x16x32_bf16(a1, bb, acc1, 0, 0, 0);
    }
    f32x4 f0 = zz, f1 = zz;
    {  // FC K-split partial of pred(t-1): 1 kstep per wave
      int ks = fcs * 4 + wv;
      const unsigned short* ap = h1o + (ks * 32 + fk);
      short8 a0 = *(const short8*)(ap + (size_t)frow * 1024);
      short8 a1 = *(const short8*)(ap + (size_t)(frow + 16) * 1024);
      short8 bb = *(const short8*)(packFC + ((size_t)fcq * 32 + ks) * 512 + lane * 8);
      f0 = __builtin_amdgcn_mfma_f32_16x16x32_bf16(a0, bb, f0, 0, 0, 0);
      f1 = __builtin_amdgcn_mfma_f32_16x16x32_bf16(a1, bb, f1, 0, 0, 0);
    }
    {
      float* r0 = red + (wv * 2 + 0) * 256;
      float* r1 = red + (wv * 2 + 1) * 256;
      float* q0 = red2 + (wv * 2 + 0) * 256;
      float* q1 = red2 + (wv * 2 + 1) * 256;
      int cc = lane & 15, rb = (lane >> 4) * 4;
#pragma unroll
      for (int q = 0; q < 4; ++q) {
        r0[(rb + q) * 16 + cc] = acc0[q];
        r1[(rb + q) * 16 + cc] = acc1[q];
        q0[(rb + q) * 16 + cc] = f0[q];
        q1[(rb + q) * 16 + cc] = f1[q];
      }
    }
    __syncthreads();
    if (tid < 128) {
      int mt = ab >> 4, rr = ab & 15;
      float g[4];
#pragma unroll
      for (int q = 0; q < 4; ++q) {
        int cc = q * 4 + au;
        float s = 0.f;
#pragma unroll
        for (int w = 0; w < 4; ++w) s += red[(w * 2 + mt) * 256 + rr * 16 + cc];
        g[q] = s + biasB[d * 2048 + q * 512 + u0 + au];
      }
      float ig = 1.f / (1.f + __expf(-g[0]));
      float fg = 1.f / (1.f + __expf(-g[1]));
      float gv = tanhf(g[2]);
      float og = 1.f / (1.f + __expf(-g[3]));
      c1 = fg * c1 + ig * gv;
      float h = og * tanhf(c1);
      unsigned int hv = (unsigned int)f2bf(h);
      unsigned int pv = (unsigned int)__shfl_xor((int)hv, 1);
      if ((au & 1) == 0) {
        unsigned int word = hv | (pv << 16);
        __hip_atomic_store((unsigned int*)(h1n + ab * 1024 + d * 512 + u0 + au),
                           word, __ATOMIC_RELAXED, __HIP_MEMORY_SCOPE_AGENT);
      }
      if (t == TT - 1) {
        hn[(size_t)((2 + d) * 32 + ab) * 512 + u0 + au] = h;
        cn[(size_t)((2 + d) * 32 + ab) * 512 + u0 + au] = c1;
      }
    } else {
      for (int ii = tid - 128; ii < 512; ii += 128) {
        int b = ii >> 4, n = ii & 15;
        int mt = b >> 4, rr = b & 15;
        float s = 0.f;
#pragma unroll
        for (int w = 0; w < 4; ++w) s += red2[(w * 2 + mt) * 256 + rr * 16 + n];
        __hip_atomic_store(&fcpart[(size_t)wg * 512 + b * 16 + n], s,
                           __ATOMIC_RELAXED, __HIP_MEMORY_SCOPE_AGENT);
      }
    }
    gridbar(flags, 2 * t + 2);
  }

  // ---- epilogue: finalize pred(510), compute pred(511) directly ----
  if (wg < 32) {
    for (int ii = tid; ii < 512; ii += 256) {
      int b = ii >> 4, n = ii & 15;
      float s = bfc[wg * 16 + n];
#pragma unroll
      for (int ss = 0; ss < 8; ++ss)
        s += fcpart[(size_t)(wg * 8 + ss) * 512 + b * 16 + n];
      out[(size_t)b * 262144 + (size_t)510 * 512 + wg * 16 + n] = s;
    }
    f32x4 acc0 = zz, acc1 = zz;
    const unsigned short* h1f = hws + 32768;  // h1(511) parity 0
    for (int kk = 0; kk < 8; ++kk) {
      int ks = wv * 8 + kk;
      const unsigned short* ap = h1f + (ks * 32 + fk);
      short8 a0 = *(const short8*)(ap + (size_t)frow * 1024);
      short8 a1 = *(const short8*)(ap + (size_t)(frow + 16) * 1024);
      short8 bb = *(const short8*)(packFC + ((size_t)wg * 32 + ks) * 512 + lane * 8);
      acc0 = __builtin_amdgcn_mfma_f32_16x16x32_bf16(a0, bb, acc0, 0, 0, 0);
      acc1 = __builtin_amdgcn_mfma_f32_16x16x32_bf16(a1, bb, acc1, 0, 0, 0);
    }
    {
      float* r0 = red + (wv * 2 + 0) * 256;
      float* r1 = red + (wv * 2 + 1) * 256;
      int cc = lane & 15, rb = (lane >> 4) * 4;
#pragma unroll
      for (int q = 0; q < 4; ++q) {
        r0[(rb + q) * 16 + cc] = acc0[q];
        r1[(rb + q) * 16 + cc] = acc1[q];
      }
    }
    __syncthreads();
    for (int ii = tid; ii < 512; ii += 256) {
      int b = ii >> 4, n = ii & 15;
      int mt = b >> 4, rr = b & 15;
      float s = bfc[wg * 16 + n];
#pragma unroll
      for (int w = 0; w < 4; ++w) s += red[(w * 2 + mt) * 256 + rr * 16 + n];
      out[(size_t)b * 262144 + (size_t)511 * 512 + wg * 16 + n] = s;
    }
  }
}

// ---------------- host ----------------

extern "C" void kernel_launch(void* const* d_in, const int* in_sizes, int n_in,
                              void* d_out, int out_size, void* d_ws,
                              size_t ws_size, hipStream_t stream) {
  const float* input_seq = (const float*)d_in[0];
  const float* W_ih = (const float*)d_in[2];
  const float* W_hh = (const float*)d_in[3];
  const float* b_ih = (const float*)d_in[4];
  const float* b_hh = (const float*)d_in[5];
  const float* W_fc = (const float*)d_in[6];
  const float* b_fc = (const float*)d_in[7];
  float* out = (float*)d_out;
  char* ws = (char*)d_ws;

  unsigned short* hws = (unsigned short*)(ws + 0);          // 256KB (2 parities)
  int* flags = (int*)(ws + 262144);                         // 1KB (poison<0 ok)
  float* fcpart = (float*)(ws + 263168);                    // 512KB
  float* biasA0 = (float*)(ws + 787456);                    // 16KB
  float* bpf = (float*)(ws + 803840);                       // 16KB
  float* biasB = (float*)(ws + 820224);                     // 16KB
  unsigned short* xbf = (unsigned short*)(ws + 1048576);    // 16MB
  unsigned short* packA = (unsigned short*)(ws + 17825792); // 16MB
  unsigned short* packB = (unsigned short*)(ws + 34603008); // 12MB
  unsigned short* packFC = (unsigned short*)(ws + 47185920);// 1MB (end ~46MB)

  (void)hipMemsetAsync(ws, 0, 131072, stream);  // zero h0/h1 parity-0
  hipLaunchKernelGGL(xconv_kernel, dim3(8192), dim3(256), 0, stream, input_seq, xbf);
  hipLaunchKernelGGL(wcomb_kernel, dim3(2048), dim3(256), 0, stream, W_ih, W_fc, packA);
  hipLaunchKernelGGL(pack_kernel, dim3(43008), dim3(256), 0, stream, W_ih, W_hh,
                     W_fc, packA, packB, packFC);
  hipLaunchKernelGGL(bias_kernel, dim3(16), dim3(256), 0, stream, W_ih, b_ih,
                     b_hh, b_fc, biasA0, bpf, biasB);

  (void)hipFuncSetAttribute((const void*)rnn_main,
                            hipFuncAttributeMaxDynamicSharedMemorySize, 131072);
  void* kargs[] = {(void*)&xbf,   (void*)&packA, (void*)&packB, (void*)&packFC,
                   (void*)&biasA0,(void*)&bpf,   (void*)&biasB, (void*)&b_fc,
                   (void*)&hws,   (void*)&fcpart,(void*)&flags, (void*)&out};
  (void)hipLaunchCooperativeKernel((void*)rnn_main, dim3(NWG), dim3(256), kargs,
                                   131072, stream);
}

// Round 3
// 10521.028 us; speedup vs baseline: 1.0566x; 1.0566x over previous
//
#include <hip/hip_runtime.h>
#include <stdint.h>

// Autoregressive bidirectional 2-layer LSTM encoder, MI355X persistent kernel.
// B=32, T=512, IN=OUT=512, LH=512 per direction, LSTM_IN=1024.
//
// Feedback folding: pred(t-1) enters layer-0 gates linearly => precompute
// Wcomb = Wp @ Wfc; recurrence then only needs h0,h1 (2 grid barriers/step).
// FC head computed as K-split partials off the critical path, finalized two
// steps later by ALL WGs (64 elements each — no arrival skew).
//
// R3: barrier redesign. Old: 65K threads poll 16 flag cachelines with sc1
// loads -> L3 queue saturation (~10us/phase, MfmaUtil 1.8%). New: wave 0
// only, dwordx4 per lane (16x less traffic), __all(min4>=gen) exit,
// acquire-fence folded into the polling wave, 2 syncthreads per barrier.

#define TT 512
#define NWG 256

typedef __attribute__((ext_vector_type(8))) short short8;
typedef __attribute__((ext_vector_type(4))) float f32x4;
typedef __attribute__((ext_vector_type(4))) unsigned short ushort4v;
typedef __attribute__((ext_vector_type(4))) float float4v;
typedef __attribute__((ext_vector_type(4))) int int4v;

__device__ __forceinline__ unsigned short f2bf(float f) {
  unsigned int u = __float_as_uint(f);
  u = (u + 0x7fffu + ((u >> 16) & 1u)) >> 16;
  return (unsigned short)u;
}

// ---------------- prep kernels ----------------

// input_seq [32][512][512] f32 -> xbf [512][32][512] bf16
__global__ void xconv_kernel(const float* __restrict__ src,
                             unsigned short* __restrict__ dst) {
  int vid = blockIdx.x * 256 + threadIdx.x;
  if (vid >= 2097152) return;
  int d0 = vid * 4;
  int t = d0 >> 14;
  int r = d0 & 16383;
  int b = r >> 9;
  int k = r & 511;
  float4v v = *(const float4v*)(src + ((size_t)(b * 512 + t) * 512 + k));
  ushort4v o;
#pragma unroll
  for (int i = 0; i < 4; ++i) o[i] = f2bf(v[i]);
  *(ushort4v*)(dst + d0) = o;
}

// Wcomb[d][r][h] = sum_o Wih[0,d,r,512+o] * Wfc[o,h], written straight into
// packedA's kstep 16..47 region in MFMA B-fragment order (bf16).
__global__ void wcomb_kernel(const float* __restrict__ Wih,
                             const float* __restrict__ Wfc,
                             unsigned short* __restrict__ packA) {
  int bid = blockIdx.x;                 // 2048 blocks
  int h = (bid & 3) * 256 + threadIdx.x;
  int rg = bid >> 2;                    // 0..511
  int d = rg >> 8;
  int r0 = (rg & 255) * 8;
  float acc[8];
#pragma unroll
  for (int i = 0; i < 8; ++i) acc[i] = 0.f;
  const float* wrow = Wih + (size_t)(d * 2048) * 1024;
  for (int o = 0; o < 512; ++o) {
    float f = Wfc[(size_t)o * 1024 + h];
#pragma unroll
    for (int i = 0; i < 8; ++i)
      acc[i] += wrow[(size_t)(r0 + i) * 1024 + 512 + o] * f;
  }
#pragma unroll
  for (int i = 0; i < 8; ++i) {
    int rr = r0 + i;
    int q = rr >> 9, u = rr & 511;
    int wg = d * 128 + (u >> 2);
    int n = q * 4 + (u & 3);
    int k = 512 + h;
    int ks = k >> 5, kin = k & 31;
    int g = kin >> 3, j = kin & 7;
    int e = (n + 16 * g) * 8 + j;
    packA[((size_t)wg * 64 + ks) * 512 + e] = f2bf(acc[i]);
  }
}

// Pack raw weights (bf16, MFMA B-fragment order):
// packedA[wg][64ks][512]: ks 0..15 = Wx (Wih L0 cols 0..511), 48..63 = Whh L0.
// packedB[wg][48ks][512]: ks 0..31 = Wih L1, 32..47 = Whh L1.
// packedFC[q][32ks][512]: Wfc tiles.
__global__ void pack_kernel(const float* __restrict__ Wih,
                            const float* __restrict__ Whh,
                            const float* __restrict__ Wfc,
                            unsigned short* __restrict__ packA,
                            unsigned short* __restrict__ packB,
                            unsigned short* __restrict__ packFC) {
  const int NA = 256 * 32 * 512;
  const int NB = 256 * 48 * 512;
  const int NFC = 32 * 32 * 512;
  int i = blockIdx.x * 256 + threadIdx.x;
  if (i < NA) {
    int wg = i >> 14;
    int rem = i & 16383;
    int ksl = rem >> 9;
    int e = rem & 511;
    int ks = (ksl < 16) ? ksl : ksl + 32;
    int l = e >> 3, j = e & 7;
    int n = l & 15, g = l >> 4;
    int k = ks * 32 + 8 * g + j;
    int d = wg >> 7, u0 = (wg & 127) << 2;
    int r = (n >> 2) * 512 + u0 + (n & 3);
    float v;
    if (k < 512) v = Wih[(size_t)(d * 2048 + r) * 1024 + k];
    else v = Whh[(size_t)(d * 2048 + r) * 512 + (k - 1536)];
    packA[((size_t)wg * 64 + ks) * 512 + e] = f2bf(v);
  } else if (i < NA + NB) {
    int ii = i - NA;
    int wg = ii / 24576;
    int rem = ii - wg * 24576;
    int ks = rem >> 9;
    int e = rem & 511;
    int l = e >> 3, j = e & 7;
    int n = l & 15, g = l >> 4;
    int k = ks * 32 + 8 * g + j;
    int d = wg >> 7, u0 = (wg & 127) << 2;
    int r = (n >> 2) * 512 + u0 + (n & 3);
    float v;
    if (k < 1024) v = Wih[(size_t)((2 + d) * 2048 + r) * 1024 + k];
    else v = Whh[(size_t)((2 + d) * 2048 + r) * 512 + (k - 1024)];
    packB[((size_t)wg * 48 + ks) * 512 + e] = f2bf(v);
  } else if (i < NA + NB + NFC) {
    int ii = i - NA - NB;
    int q = ii >> 14;
    int rem = ii & 16383;
    int ks = rem >> 9;
    int e = rem & 511;
    int l = e >> 3, j = e & 7;
    int n = l & 15, g = l >> 4;
    int k = ks * 32 + 8 * g + j;
    int o = q * 16 + n;
    packFC[((size_t)q * 32 + ks) * 512 + e] = f2bf(Wfc[(size_t)o * 1024 + k]);
  }
}

// biasA0 = bih+bhh (L0); bpf = Wp @ bfc (added for t>0); biasB = bih+bhh (L1)
__global__ void bias_kernel(const float* __restrict__ Wih,
                            const float* __restrict__ bih,
                            const float* __restrict__ bhh,
                            const float* __restrict__ bfc,
                            float* __restrict__ biasA0,
                            float* __restrict__ bpf,
                            float* __restrict__ biasB) {
  int r = blockIdx.x * 256 + threadIdx.x;  // 4096
  int d = r >> 11, rr = r & 2047;
  biasA0[r] = bih[d * 2048 + rr] + bhh[d * 2048 + rr];
  biasB[r] = bih[(2 + d) * 2048 + rr] + bhh[(2 + d) * 2048 + rr];
  float s = 0.f;
  const float* w = Wih + (size_t)(d * 2048 + rr) * 1024 + 512;
  for (int o = 0; o < 512; ++o) s += w[o] * bfc[o];
  bpf[r] = s;
}

// ---------------- main persistent kernel ----------------

__device__ __forceinline__ int4v flag_load4(const int* p) {
  int4v r;
  asm volatile("global_load_dwordx4 %0, %1, off sc0 sc1\n\ts_waitcnt vmcnt(0)"
               : "=v"(r)
               : "v"(p)
               : "memory");
  return r;
}

__device__ __forceinline__ void gridbar(int* flags, int gen) {
  __syncthreads();  // all waves drain vmcnt (sc1 h-stores done) before signal
  if (threadIdx.x == 0)
    __hip_atomic_store(&flags[blockIdx.x], gen, __ATOMIC_RELAXED,
                       __HIP_MEMORY_SCOPE_AGENT);
  if (threadIdx.x < 64) {  // wave 0 polls all 256 flags, 4 per lane
    const int* p = flags + threadIdx.x * 4;
    for (;;) {
      int4v v = flag_load4(p);
      int m0 = v[0] < v[1] ? v[0] : v[1];
      int m1 = v[2] < v[3] ? v[2] : v[3];
      int m = m0 < m1 ? m0 : m1;
      if (__all(m >= gen)) break;
      __builtin_amdgcn_s_sleep(2);
    }
    // one acquire (buffer_inv) per WG: invalidate stale L1/L2 lines
    __builtin_amdgcn_fence(__ATOMIC_ACQUIRE, "agent");
  }
  __syncthreads();
}

__global__ __launch_bounds__(256, 1) void rnn_main(
    const unsigned short* __restrict__ xbf,
    const unsigned short* __restrict__ packA,
    const unsigned short* __restrict__ packB,
    const unsigned short* __restrict__ packFC,
    const float* __restrict__ biasA0, const float* __restrict__ bpf,
    const float* __restrict__ biasB, const float* __restrict__ bfc,
    unsigned short* __restrict__ hws, float* __restrict__ fcpart,
    int* __restrict__ flags, float* __restrict__ dout) {
  extern __shared__ unsigned short lds[];
  unsigned short* wA = lds;            // 64*512 bf16 = 64KB
  unsigned short* wB = wA + 64 * 512;  // 48*512 bf16 = 48KB
  float* red = (float*)(wB + 48 * 512);  // 2048 f32
  float* red2 = red + 2048;              // 2048 f32  (total 128KB)

  const int wg = blockIdx.x;
  const int tid = threadIdx.x;
  const int wv = tid >> 6;
  const int lane = tid & 63;
  const int d = wg >> 7;
  const int u0 = (wg & 127) << 2;
  const int frow = lane & 15;
  const int fk = (lane >> 4) << 3;
  const int fcq = wg >> 3;
  const int fcs = wg & 7;

  {  // stage LDS-resident weights
    const uint4* s = (const uint4*)(packA + (size_t)wg * (64 * 512));
    uint4* dd = (uint4*)wA;
    for (int i = tid; i < 4096; i += 256) dd[i] = s[i];
    const uint4* s2 = (const uint4*)(packB + (size_t)wg * (48 * 512));
    uint4* dd2 = (uint4*)wB;
    for (int i = tid; i < 3072; i += 256) dd2[i] = s2[i];
  }
  __syncthreads();

  float c0 = 0.f, c1 = 0.f;  // cell state, persistent in registers
  const int ab = tid >> 2;   // batch (tid<128)
  const int au = tid & 3;    // unit-in-4

  float* out = dout;
  float* hn = dout + (size_t)32 * 512 * 512;
  float* cn = hn + 4 * 32 * 512;
  f32x4 zz = {0.f, 0.f, 0.f, 0.f};

  for (int t = 0; t < TT; ++t) {
    const int oldp = t & 1;
    const unsigned short* h0o = hws + oldp * 65536;
    const unsigned short* h1o = h0o + 32768;
    unsigned short* h0n = hws + (oldp ^ 1) * 65536;
    unsigned short* h1n = h0n + 32768;

    // finalize pred(t-2) from fcpart — distributed: 64 outputs per WG,
    // one per lane of wave 0 (uniform work, no arrival skew)
    if (t >= 2 && tid < 64) {
      int e = wg * 64 + tid;  // 0..16383 = b*512 + o
      int b = e >> 9, o = e & 511;
      int oq = o >> 4, n = o & 15;
      float s = bfc[o];
#pragma unroll
      for (int ss = 0; ss < 8; ++ss)
        s += fcpart[(size_t)(oq * 8 + ss) * 512 + b * 16 + n];
      out[(size_t)b * 262144 + (size_t)(t - 2) * 512 + o] = s;
    }

    // ---- Phase A: layer-0 gates. K = [x 512 | h1@Wcomb 1024 | h0dir 512]
    f32x4 acc0 = zz, acc1 = zz;
    {
      const unsigned short* xb = xbf + (size_t)t * 16384;
      const unsigned short* abase;
      int astride;
      if (wv == 0) { abase = xb; astride = 512; }
      else if (wv == 3) { abase = h0o + d * 512; astride = 1024; }
      else { abase = h1o + (wv - 1) * 512; astride = 1024; }
      for (int li = 0; li < 16; ++li) {
        const unsigned short* ap = abase + li * 32 + fk;
        short8 a0 = *(const short8*)(ap + (size_t)frow * astride);
        short8 a1 = *(const short8*)(ap + (size_t)(frow + 16) * astride);
        short8 bb = *(const short8*)(wA + (wv * 16 + li) * 512 + lane * 8);
        acc0 = __builtin_amdgcn_mfma_f32_16x16x32_bf16(a0, bb, acc0, 0, 0, 0);
        acc1 = __builtin_amdgcn_mfma_f32_16x16x32_bf16(a1, bb, acc1, 0, 0, 0);
      }
    }
    {
      float* r0 = red + (wv * 2 + 0) * 256;
      float* r1 = red + (wv * 2 + 1) * 256;
      int cc = lane & 15, rb = (lane >> 4) * 4;
#pragma unroll
      for (int q = 0; q < 4; ++q) {
        r0[(rb + q) * 16 + cc] = acc0[q];
        r1[(rb + q) * 16 + cc] = acc1[q];
      }
    }
    __syncthreads();
    if (tid < 128) {
      int mt = ab >> 4, rr = ab & 15;
      float g[4];
#pragma unroll
      for (int q = 0; q < 4; ++q) {
        int cc = q * 4 + au;
        float s = 0.f;
#pragma unroll
        for (int w = 0; w < 4; ++w) s += red[(w * 2 + mt) * 256 + rr * 16 + cc];
        int gi = d * 2048 + q * 512 + u0 + au;
        s += biasA0[gi];
        if (t > 0) s += bpf[gi];
        g[q] = s;
      }
      float ig = 1.f / (1.f + __expf(-g[0]));
      float fg = 1.f / (1.f + __expf(-g[1]));
      float gv = tanhf(g[2]);
      float og = 1.f / (1.f + __expf(-g[3]));
      c0 = fg * c0 + ig * gv;
      float h = og * tanhf(c0);
      unsigned int hv = (unsigned int)f2bf(h);
      unsigned int pv = (unsigned int)__shfl_xor((int)hv, 1);
      if ((au & 1) == 0) {
        unsigned int word = hv | (pv << 16);
        __hip_atomic_store((unsigned int*)(h0n + ab * 1024 + d * 512 + u0 + au),
                           word, __ATOMIC_RELAXED, __HIP_MEMORY_SCOPE_AGENT);
      }
      if (t == TT - 1) {
        hn[(size_t)(d * 32 + ab) * 512 + u0 + au] = h;
        cn[(size_t)(d * 32 + ab) * 512 + u0 + au] = c0;
      }
    }
    gridbar(flags, 2 * t + 1);

    // ---- Phase B: layer-1 gates (K = [h0 1024 | h1dir 512]) + FC partials
    acc0 = zz; acc1 = zz;
    for (int kk = 0; kk < 12; ++kk) {
      int ks = wv * 12 + kk;
      const unsigned short* ap = (ks < 32)
          ? (h0n + ks * 32 + fk)
          : (h1o + d * 512 + (ks - 32) * 32 + fk);
      short8 a0 = *(const short8*)(ap + (size_t)frow * 1024);
      short8 a1 = *(const short8*)(ap + (size_t)(frow + 16) * 1024);
      short8 bb = *(const short8*)(wB + ks * 512 + lane * 8);
      acc0 = __builtin_amdgcn_mfma_f32_16x16x32_bf16(a0, bb, acc0, 0, 0, 0);
      acc1 = __builtin_amdgcn_mfma_f32_16x16x32_bf16(a1, bb, acc1, 0, 0, 0);
    }
    f32x4 f0 = zz, f1 = zz;
    {  // FC K-split partial of pred(t-1): 1 kstep per wave
      int ks = fcs * 4 + wv;
      const unsigned short* ap = h1o + (ks * 32 + fk);
      short8 a0 = *(const short8*)(ap + (size_t)frow * 1024);
      short8 a1 = *(const short8*)(ap + (size_t)(frow + 16) * 1024);
      short8 bb = *(const short8*)(packFC + ((size_t)fcq * 32 + ks) * 512 + lane * 8);
      f0 = __builtin_amdgcn_mfma_f32_16x16x32_bf16(a0, bb, f0, 0, 0, 0);
      f1 = __builtin_amdgcn_mfma_f32_16x16x32_bf16(a1, bb, f1, 0, 0, 0);
    }
    {
      float* r0 = red + (wv * 2 + 0) * 256;
      float* r1 = red + (wv * 2 + 1) * 256;
      float* q0 = red2 + (wv * 2 + 0) * 256;
      float* q1 = red2 + (wv * 2 + 1) * 256;
      int cc = lane & 15, rb = (lane >> 4) * 4;
#pragma unroll
      for (int q = 0; q < 4; ++q) {
        r0[(rb + q) * 16 + cc] = acc0[q];
        r1[(rb + q) * 16 + cc] = acc1[q];
        q0[(rb + q) * 16 + cc] = f0[q];
        q1[(rb + q) * 16 + cc] = f1[q];
      }
    }
    __syncthreads();
    if (tid < 128) {
      int mt = ab >> 4, rr = ab & 15;
      float g[4];
#pragma unroll
      for (int q = 0; q < 4; ++q) {
        int cc = q * 4 + au;
        float s = 0.f;
#pragma unroll
        for (int w = 0; w < 4; ++w) s += red[(w * 2 + mt) * 256 + rr * 16 + cc];
        g[q] = s + biasB[d * 2048 + q * 512 + u0 + au];
      }
      float ig = 1.f / (1.f + __expf(-g[0]));
      float fg = 1.f / (1.f + __expf(-g[1]));
      float gv = tanhf(g[2]);
      float og = 1.f / (1.f + __expf(-g[3]));
      c1 = fg * c1 + ig * gv;
      float h = og * tanhf(c1);
      unsigned int hv = (unsigned int)f2bf(h);
      unsigned int pv = (unsigned int)__shfl_xor((int)hv, 1);
      if ((au & 1) == 0) {
        unsigned int word = hv | (pv << 16);
        __hip_atomic_store((unsigned int*)(h1n + ab * 1024 + d * 512 + u0 + au),
                           word, __ATOMIC_RELAXED, __HIP_MEMORY_SCOPE_AGENT);
      }
      if (t == TT - 1) {
        hn[(size_t)((2 + d) * 32 + ab) * 512 + u0 + au] = h;
        cn[(size_t)((2 + d) * 32 + ab) * 512 + u0 + au] = c1;
      }
    } else {
      for (int ii = tid - 128; ii < 512; ii += 128) {
        int b = ii >> 4, n = ii & 15;
        int mt = b >> 4, rr = b & 15;
        float s = 0.f;
#pragma unroll
        for (int w = 0; w < 4; ++w) s += red2[(w * 2 + mt) * 256 + rr * 16 + n];
        __hip_atomic_store(&fcpart[(size_t)wg * 512 + b * 16 + n], s,
                           __ATOMIC_RELAXED, __HIP_MEMORY_SCOPE_AGENT);
      }
    }
    gridbar(flags, 2 * t + 2);
  }

  // ---- epilogue: finalize pred(510) (distributed), pred(511) by wg<32 ----
  if (tid < 64) {
    int e = wg * 64 + tid;
    int b = e >> 9, o = e & 511;
    int oq = o >> 4, n = o & 15;
    float s = bfc[o];
#pragma unroll
    for (int ss = 0; ss < 8; ++ss)
      s += fcpart[(size_t)(oq * 8 + ss) * 512 + b * 16 + n];
    out[(size_t)b * 262144 + (size_t)510 * 512 + o] = s;
  }
  if (wg < 32) {
    f32x4 acc0 = zz, acc1 = zz;
    const unsigned short* h1f = hws + 32768;  // h1(511) parity 0
    for (int kk = 0; kk < 8; ++kk) {
      int ks = wv * 8 + kk;
      const unsigned short* ap = h1f + (ks * 32 + fk);
      short8 a0 = *(const short8*)(ap + (size_t)frow * 1024);
      short8 a1 = *(const short8*)(ap + (size_t)(frow + 16) * 1024);
      short8 bb = *(const short8*)(packFC + ((size_t)wg * 32 + ks) * 512 + lane * 8);
      acc0 = __builtin_amdgcn_mfma_f32_16x16x32_bf16(a0, bb, acc0, 0, 0, 0);
      acc1 = __builtin_amdgcn_mfma_f32_16x16x32_bf16(a1, bb, acc1, 0, 0, 0);
    }
    {
      float* r0 = red + (wv * 2 + 0) * 256;
      float* r1 = red + (wv * 2 + 1) * 256;
      int cc = lane & 15, rb = (lane >> 4) * 4;
#pragma unroll
      for (int q = 0; q < 4; ++q) {
        r0[(rb + q) * 16 + cc] = acc0[q];
        r1[(rb + q) * 16 + cc] = acc1[q];
      }
    }
    __syncthreads();
    for (int ii = tid; ii < 512; ii += 256) {
      int b = ii >> 4, n = ii & 15;
      int mt = b >> 4, rr = b & 15;
      float s = bfc[wg * 16 + n];
#pragma unroll
      for (int w = 0; w < 4; ++w) s += red[(w * 2 + mt) * 256 + rr * 16 + n];
      out[(size_t)b * 262144 + (size_t)511 * 512 + wg * 16 + n] = s;
    }
  }
}

// ---------------- host ----------------

extern "C" void kernel_launch(void* const* d_in, const int* in_sizes, int n_in,
                              void* d_out, int out_size, void* d_ws,
                              size_t ws_size, hipStream_t stream) {
  const float* input_seq = (const float*)d_in[0];
  const float* W_ih = (const float*)d_in[2];
  const float* W_hh = (const float*)d_in[3];
  const float* b_ih = (const float*)d_in[4];
  const float* b_hh = (const float*)d_in[5];
  const float* W_fc = (const float*)d_in[6];
  const float* b_fc = (const float*)d_in[7];
  float* out = (float*)d_out;
  char* ws = (char*)d_ws;

  unsigned short* hws = (unsigned short*)(ws + 0);          // 256KB (2 parities)
  int* flags = (int*)(ws + 262144);                         // 1KB (poison<0 ok)
  float* fcpart = (float*)(ws + 263168);                    // 512KB
  float* biasA0 = (float*)(ws + 787456);                    // 16KB
  float* bpf = (float*)(ws + 803840);                       // 16KB
  float* biasB = (float*)(ws + 820224);                     // 16KB
  unsigned short* xbf = (unsigned short*)(ws + 1048576);    // 16MB
  unsigned short* packA = (unsigned short*)(ws + 17825792); // 16MB
  unsigned short* packB = (unsigned short*)(ws + 34603008); // 12MB
  unsigned short* packFC = (unsigned short*)(ws + 47185920);// 1MB (end ~46MB)

  (void)hipMemsetAsync(ws, 0, 131072, stream);  // zero h0/h1 parity-0
  hipLaunchKernelGGL(xconv_kernel, dim3(8192), dim3(256), 0, stream, input_seq, xbf);
  hipLaunchKernelGGL(wcomb_kernel, dim3(2048), dim3(256), 0, stream, W_ih, W_fc, packA);
  hipLaunchKernelGGL(pack_kernel, dim3(43008), dim3(256), 0, stream, W_ih, W_hh,
                     W_fc, packA, packB, packFC);
  hipLaunchKernelGGL(bias_kernel, dim3(16), dim3(256), 0, stream, W_ih, b_ih,
                     b_hh, b_fc, biasA0, bpf, biasB);

  (void)hipFuncSetAttribute((const void*)rnn_main,
                            hipFuncAttributeMaxDynamicSharedMemorySize, 131072);
  void* kargs[] = {(void*)&xbf,   (void*)&packA, (void*)&packB, (void*)&packFC,
                   (void*)&biasA0,(void*)&bpf,   (void*)&biasB, (void*)&b_fc,
                   (void*)&hws,   (void*)&fcpart,(void*)&flags, (void*)&out};
  (void)hipLaunchCooperativeKernel((void*)rnn_main, dim3(NWG), dim3(256), kargs,
                                   131072, stream);
}